// Round 6
// baseline (2364.871 us; speedup 1.0000x reference)
//
#include <hip/hip_runtime.h>
#include <stdint.h>

#define T_STEPS 512
#define BATCH   512
#define DIN     128
#define HID     256
#define NCLS    1000

typedef unsigned int u32;
typedef unsigned long long u64;
typedef __attribute__((ext_vector_type(8))) short  short8;
typedef __attribute__((ext_vector_type(4))) short  short4v;
typedef __attribute__((ext_vector_type(4))) float  f32x4;

__device__ __forceinline__ short f2bf(float f){
  u32 u = __float_as_uint(f);
  u32 r = (u + 0x7FFFu + ((u >> 16) & 1u)) >> 16;   // RNE
  return (short)r;
}
__device__ __forceinline__ float bf2f(unsigned short s){
  return __uint_as_float(((u32)s) << 16);
}
__device__ __forceinline__ short8 cvt8(f32x4 a, f32x4 b){
  short8 v;
  v[0]=f2bf(a[0]); v[1]=f2bf(a[1]); v[2]=f2bf(a[2]); v[3]=f2bf(a[3]);
  v[4]=f2bf(b[0]); v[5]=f2bf(b[1]); v[6]=f2bf(b[2]); v[7]=f2bf(b[3]);
  return v;
}

// ---------------------------------------------------------------------------
// Pack W_ih (768x128) / W_hh (768x256) fp32 -> bf16 frags P[kb][j][0..7],
// frag(kt,g4,j) = P[kt*4+g4][j]  (validated layout: R1/R3/R5 passed).
// ---------------------------------------------------------------------------
__global__ __launch_bounds__(256) void pack_weights(
    const float* __restrict__ Wih, const float* __restrict__ Whh,
    short* __restrict__ PIH, short* __restrict__ PHH)
{
  int idx = blockIdx.x * 256 + threadIdx.x;   // 16*768 + 32*768
  if (idx >= 48*768) return;
  const float* src; short* dst;
  if (idx < 16*768){
    int kb = idx / 768, j = idx - kb*768;
    src = Wih + (size_t)j*DIN + kb*8;
    dst = PIH + (size_t)idx*8;
  } else {
    int i2 = idx - 16*768;
    int kb = i2 / 768, j = i2 - kb*768;
    src = Whh + (size_t)j*HID + kb*8;
    dst = PHH + (size_t)i2*8;
  }
  short8 v;
  #pragma unroll
  for (int e=0;e<8;e++) v[e] = f2bf(src[e]);
  *(short8*)dst = v;
}

// ---------------------------------------------------------------------------
// drop_mask fp32 (T,B,H) -> bitmask MB[t][gb(=b>>3)][r(=b&7)][32B], 1 bit/u.
// ---------------------------------------------------------------------------
__global__ __launch_bounds__(256) void mask_bits(
    const float* __restrict__ mask, unsigned char* __restrict__ MBo)
{
  int idx = blockIdx.x*256 + threadIdx.x;      // 512*512*32 = 8388608
  int t = idx >> 14, rem = idx & 16383, bb = rem >> 5, ub = rem & 31;
  const float* mp = mask + ((size_t)t*BATCH + bb)*HID + ub*8;
  u32 byte = 0;
  #pragma unroll
  for (int e=0;e<8;e++) byte |= (mp[e] > 0.5f ? 1u : 0u) << e;
  MBo[((size_t)t*64 + (bb>>3))*256 + (bb&7)*32 + ub] = (unsigned char)byte;
}

// ---------------------------------------------------------------------------
// gi = x @ W_ih^T + b_ih (+ b_hh for r,z).  Per (gb,t) output image (8KB+8KB):
//   RZ bf16: row b (8) x 512 cols (r: j<256, z: j-256)
//   N  fp32: row b (8) x 256 cols
// Spill acc -> LDS image tiles -> fully-coalesced 16B/lane global stores.
// ---------------------------------------------------------------------------
__global__ __launch_bounds__(512, 1) void gi_gemm(
    const float* __restrict__ x, const float* __restrict__ b_ih,
    const float* __restrict__ b_hh, const short* __restrict__ PIH,
    short* __restrict__ GIbf, float* __restrict__ GIn)
{
  __shared__ __align__(16) short XT[64*136];   // A-tile bf16      17408 B
  __shared__ __align__(16) short ORZ[16*520];  // RZ images, pad   16640 B
  __shared__ __align__(16) float ON [16*264];  // N  images, pad   16896 B
  const int tid = threadIdx.x;
  const int gb  = blockIdx.x >> 6;
  const int tc  = blockIdx.x & 63;
  const int tp0 = tc*4;
  const int w = tid>>6, l = tid&63, c = l&15, g4 = l>>4;

  // B-fragments (held across block) + folded bias
  short8 bfr[6][4]; float bj[6];
  #pragma unroll
  for (int q=0;q<6;q++){
    const int j = (w*6+q)*16 + c;
    #pragma unroll
    for (int kt=0;kt<4;kt++)
      bfr[q][kt] = *(const short8*)(PIH + ((size_t)(kt*4+g4)*768 + j)*8);
    bj[q] = b_ih[j] + (j < 512 ? b_hh[j] : 0.f);
  }

  // stage A: 64 rows x 128 k (fp32 -> bf16); row = tpl*16 + tt*8 + r
  {
    const int row = tid>>3, cc = (tid&7)*16;
    const int r = row&7, tpl = row>>4, tt = (row>>3)&1;
    const int bb = gb*8 + r;
    const int t  = (tp0+tpl)*2 + tt;
    const float* src = x + ((size_t)bb*T_STEPS + t)*DIN + cc;
    f32x4 a0 = *(const f32x4*)src,     a1 = *(const f32x4*)(src+4);
    f32x4 a2 = *(const f32x4*)(src+8), a3 = *(const f32x4*)(src+12);
    *(short8*)&XT[row*136 + cc]     = cvt8(a0,a1);
    *(short8*)&XT[row*136 + cc + 8] = cvt8(a2,a3);
  }
  __syncthreads();

  const f32x4 z4 = {0.f,0.f,0.f,0.f};
  #pragma unroll 1
  for (int mt=0; mt<4; ++mt){
    f32x4 acc[6];
    #pragma unroll
    for (int q=0;q<6;q++) acc[q] = z4;
    #pragma unroll
    for (int kt=0;kt<4;kt++){
      short8 af = *(const short8*)&XT[(mt*16+c)*136 + kt*32 + g4*8];
      #pragma unroll
      for (int q=0;q<6;q++)
        acc[q] = __builtin_amdgcn_mfma_f32_16x16x32_bf16(af, bfr[q][kt], acc[q], 0,0,0);
    }
    // spill to LDS images (C/D: col=c -> j, row16 = g4*4+i)
    #pragma unroll
    for (int q=0;q<6;q++){
      const int j = (w*6+q)*16 + c;
      #pragma unroll
      for (int i=0;i<4;i++){
        const int r16 = g4*4+i;
        const float v = acc[q][i] + bj[q];
        if (j < 512) ORZ[r16*520 + j] = f2bf(v);
        else         ON [r16*264 + (j-512)] = v;
      }
    }
    __syncthreads();
    // copy out, fully coalesced 16B/lane
    {
      const size_t gbase = (size_t)gb*2097152;   // shorts
      #pragma unroll
      for (int pass=0; pass<2; ++pass){
        const int chunk = pass*512 + tid;        // 0..1023 over 2 images
        const int tt  = chunk >> 9;
        const int rem = chunk & 511;             // 16B-chunk in 8KB image
        const int row = rem >> 6, c16 = rem & 63;
        short8 vv = *(const short8*)&ORZ[(tt*8+row)*520 + c16*8];
        const int t = (tp0+mt)*2 + tt;
        *(short8*)(GIbf + gbase + (size_t)t*4096 + rem*8) = vv;
      }
      const size_t nbase = (size_t)gb*1048576;   // floats
      #pragma unroll
      for (int pass=0; pass<2; ++pass){
        const int chunk = pass*512 + tid;
        const int tt  = chunk >> 9;
        const int rem = chunk & 511;
        const int row = rem >> 6, c4 = rem & 63;
        f32x4 vv = *(const f32x4*)&ON[(tt*8+row)*264 + c4*4];
        const int t = (tp0+mt)*2 + tt;
        *(f32x4*)(GIn + nbase + (size_t)t*2048 + rem*4) = vv;
      }
    }
    __syncthreads();
  }
}

// ---------------------------------------------------------------------------
// Persistent scan: 64 blocks x 8 batch rows, 512 thr (8 waves).
// W_hh register-resident (192 VGPR/lane, pinned by memory clobber).
// gi prefetched into REGISTERS one step ahead (compiler-tracked waits),
// committed to single-buffer LDS at step start.  2 raw barriers/step,
// lgkmcnt-only; global loads stay in flight across them.
// ---------------------------------------------------------------------------
__global__ __launch_bounds__(512, 2) void gru_scan(
    const float* __restrict__ b_hh, const unsigned char* __restrict__ MB,
    const short* __restrict__ PHH, const short* __restrict__ GIbf,
    const float* __restrict__ GIn, float* __restrict__ HFIN)
{
  __shared__ __align__(16) short Ah[16*264];     // h bf16 A-tile (rows 8..15 zero)
  __shared__ __align__(16) float Gs[8*776];      // gh spill
  __shared__ __align__(16) short GiRZs[8*512];   // gi r,z bf16 (single buffer)
  __shared__ __align__(16) float GiNs [8*256];   // gi n fp32

  const int tid = threadIdx.x;
  const int gb  = blockIdx.x;
  const int w = tid>>6, l = tid&63, c = l&15, g4 = l>>4;

  // ---- W_hh fragments -> registers (once) ----
  short8 whf[6][8];
  #pragma unroll
  for (int q=0;q<6;q++){
    const int j = (w*6+q)*16 + c;
    #pragma unroll
    for (int kt=0;kt<8;kt++)
      whf[q][kt] = *(const short8*)(PHH + ((size_t)(kt*4+g4)*768 + j)*8);
  }

  const int b  = tid>>6;
  const int u4 = (tid&63)*4;
  const f32x4 bhn4 = *(const f32x4*)(b_hh + 512 + u4);
  const int mboff = b*32 + ((tid&63)>>1);
  const int mshift = ((tid&63)&1) << 2;

  for (int i=tid; i<16*264; i+=512) Ah[i] = 0;

  const char* srz = (const char*)GIbf + (size_t)gb*4194304;
  const char* sn  = (const char*)GIn  + (size_t)gb*4194304;
  const int gioff = w*1024 + l*16;
  const int ar_off = c*264;
  const int gbase = (g4*4)*776 + w*96 + c;       // Gs spill base (g4<2)

  // pin whf/biases in registers: after this clobber, re-loading is illegal
  asm volatile("" ::: "memory");

  // ---- prologue: fetch gi(0), mask(0) into regs ----
  short8 rzA = *(const short8*)(srz + gioff);
  f32x4  nA  = *(const f32x4 *)(sn  + gioff);
  u32    mkA = MB[(size_t)gb*256 + mboff];
  short8 rzB; f32x4 nB; u32 mkB;
  float hreg[4] = {0.f,0.f,0.f,0.f};
  __syncthreads();   // Ah init visible

  const f32x4 z4 = {0.f,0.f,0.f,0.f};

#define STEP(T, RZC, NC, MC, RZN, NN, MN) {                                    \
  const int tn = ((T) < T_STEPS-1) ? (T)+1 : (T);                              \
  /* A: commit gi(T) regs -> LDS (row w, intra-wave) */                        \
  *(short8*)&GiRZs[w*512 + l*8] = RZC;                                         \
  *(f32x4 *)&GiNs [w*256 + l*4] = NC;                                          \
  /* B: fetch gi(T+1) into regs (in flight across both barriers) */            \
  RZN = *(const short8*)(srz + (size_t)tn*8192 + gioff);                       \
  NN  = *(const f32x4 *)(sn  + (size_t)tn*8192 + gioff);                      \
  MN  = MB[((size_t)tn*64 + gb)*256 + mboff];                                  \
  /* C: gh = h @ W_hh^T : 48 MFMA / wave */                                    \
  f32x4 acc[6];                                                                \
  _Pragma("unroll") for (int q=0;q<6;q++) acc[q] = z4;                         \
  _Pragma("unroll") for (int kt=0;kt<8;kt++){                                  \
    short8 af = *(const short8*)&Ah[ar_off + kt*32 + g4*8];                    \
    _Pragma("unroll") for (int q=0;q<6;q++)                                    \
      acc[q] = __builtin_amdgcn_mfma_f32_16x16x32_bf16(af, whf[q][kt], acc[q], 0,0,0); \
  }                                                                            \
  /* D: spill rows 0..7 (C/D: col=c, row=g4*4+i) */                            \
  if (g4 < 2){                                                                 \
    _Pragma("unroll") for (int q=0;q<6;q++){                                   \
      _Pragma("unroll") for (int i=0;i<4;i++)                                  \
        Gs[gbase + i*776 + q*16] = acc[q][i];                                  \
    }                                                                          \
  }                                                                            \
  /* E: mid barrier (LDS only; VMEM stays in flight) */                        \
  asm volatile("s_waitcnt lgkmcnt(0)" ::: "memory");                           \
  __builtin_amdgcn_sched_barrier(0);                                           \
  __builtin_amdgcn_s_barrier();                                                \
  __builtin_amdgcn_sched_barrier(0);                                           \
  /* F: gates */                                                               \
  {                                                                            \
    f32x4 gr = *(const f32x4*)&Gs[b*776       + u4];                           \
    f32x4 gz = *(const f32x4*)&Gs[b*776 + 256 + u4];                           \
    f32x4 gn = *(const f32x4*)&Gs[b*776 + 512 + u4];                           \
    short4v sr = *(const short4v*)&GiRZs[b*512       + u4];                    \
    short4v sz = *(const short4v*)&GiRZs[b*512 + 256 + u4];                    \
    f32x4 gin = *(const f32x4*)&GiNs[b*256 + u4];                              \
    _Pragma("unroll") for (int e=0;e<4;e++){                                   \
      float r_ = 1.f/(1.f + __expf(-(gr[e] + bf2f((unsigned short)sr[e]))));   \
      float z_ = 1.f/(1.f + __expf(-(gz[e] + bf2f((unsigned short)sz[e]))));   \
      float e2 = __expf(2.f*(gin[e] + r_*(gn[e] + bhn4[e])));                  \
      float n_ = 1.f - 2.f/(e2 + 1.f);                                         \
      float mv = ((MC >> (mshift + e)) & 1u) ? 1.3333334f : 0.f;               \
      hreg[e] = ((1.f - z_)*n_ + z_*hreg[e]) * mv;                             \
    }                                                                          \
    short4v hv;                                                                \
    hv[0]=f2bf(hreg[0]); hv[1]=f2bf(hreg[1]);                                  \
    hv[2]=f2bf(hreg[2]); hv[3]=f2bf(hreg[3]);                                  \
    *(short4v*)&Ah[b*264 + u4] = hv;                                           \
  }                                                                            \
  /* G: end barrier (LDS only) */                                              \
  asm volatile("s_waitcnt lgkmcnt(0)" ::: "memory");                           \
  __builtin_amdgcn_sched_barrier(0);                                           \
  __builtin_amdgcn_s_barrier();                                                \
  __builtin_amdgcn_sched_barrier(0);                                           \
}

  for (int t2=0; t2<T_STEPS; t2+=2){
    STEP(t2,   rzA, nA, mkA, rzB, nB, mkB);
    STEP(t2+1, rzB, nB, mkB, rzA, nA, mkA);
  }
#undef STEP

  f32x4 hv; hv[0]=hreg[0]; hv[1]=hreg[1]; hv[2]=hreg[2]; hv[3]=hreg[3];
  *(f32x4*)&HFIN[((size_t)(gb*8 + b))*HID + u4] = hv;
}

// ---------------------------------------------------------------------------
// out = h @ W_out^T + b_out   (512x256 @ 256x1000), fp32 vector.
// ---------------------------------------------------------------------------
__global__ __launch_bounds__(256) void out_gemm(
    const float* __restrict__ Hf, const float* __restrict__ Wout,
    const float* __restrict__ bout, float* __restrict__ out)
{
  __shared__ __align__(16) float hl[16*256];
  const int bb0 = (blockIdx.x >> 4) * 16;
  const int cc0 = (blockIdx.x & 15) * 64;
  for (int i=threadIdx.x; i<16*256; i+=256) hl[i] = Hf[(size_t)bb0*HID + i];
  __syncthreads();
  const int cc = cc0 + (threadIdx.x & 63);
  const int br = threadIdx.x >> 6;
  if (cc >= NCLS) return;
  const f32x4* wr = (const f32x4*)(Wout + (size_t)cc*HID);
  float a0=0.f, a1=0.f, a2=0.f, a3=0.f;
  #pragma unroll 8
  for (int k4=0;k4<64;k4++){
    f32x4 wv = wr[k4];
    #pragma unroll
    for (int e=0;e<4;e++){
      float we = wv[e]; int k = k4*4+e;
      a0 += hl[(br   )*256+k]*we;
      a1 += hl[(br+ 4)*256+k]*we;
      a2 += hl[(br+ 8)*256+k]*we;
      a3 += hl[(br+12)*256+k]*we;
    }
  }
  float bo = bout[cc];
  out[(size_t)(bb0+br   )*NCLS + cc] = a0 + bo;
  out[(size_t)(bb0+br+ 4)*NCLS + cc] = a1 + bo;
  out[(size_t)(bb0+br+ 8)*NCLS + cc] = a2 + bo;
  out[(size_t)(bb0+br+12)*NCLS + cc] = a3 + bo;
}

// ---------------------------------------------------------------------------
extern "C" void kernel_launch(void* const* d_in, const int* in_sizes, int n_in,
                              void* d_out, int out_size, void* d_ws, size_t ws_size,
                              hipStream_t stream) {
  const float* x     = (const float*)d_in[0];
  const float* W_ih  = (const float*)d_in[1];
  const float* W_hh  = (const float*)d_in[2];
  const float* b_ih  = (const float*)d_in[3];
  const float* b_hh  = (const float*)d_in[4];
  const float* W_out = (const float*)d_in[5];
  const float* b_out = (const float*)d_in[6];
  const float* dmask = (const float*)d_in[7];

  // ws layout (bytes):
  //   PIH   0         .. 196608
  //   PHH   196608    .. 589824
  //   HFIN  589824    .. 1114112
  //   MB    1114112   .. 9502720
  //   GIbf  9502720   .. 277938176   (64 gb * 512 t * 8KB)
  //   GIn   277938176 .. 546373632   (64 gb * 512 t * 8KB)
  if (ws_size < 546373632ull) return;   // clean fail if scratch too small
  short* PIH  = (short*)d_ws;
  short* PHH  = (short*)((char*)d_ws + 196608);
  float* HFIN = (float*)((char*)d_ws + 589824);
  unsigned char* MBp = (unsigned char*)d_ws + 1114112;
  short* GIbf = (short*)((char*)d_ws + 9502720);
  float* GIn  = (float*)((char*)d_ws + 277938176);

  pack_weights<<<144, 256, 0, stream>>>(W_ih, W_hh, PIH, PHH);
  mask_bits<<<32768, 256, 0, stream>>>(dmask, MBp);
  gi_gemm<<<4096, 512, 0, stream>>>(x, b_ih, b_hh, PIH, GIbf, GIn);
  gru_scan<<<64, 512, 0, stream>>>(b_hh, MBp, PHH, GIbf, GIn, HFIN);
  out_gemm<<<512, 256, 0, stream>>>(HFIN, W_out, b_out, (float*)d_out);
}

// Round 7
// 2201.765 us; speedup vs baseline: 1.0741x; 1.0741x over previous
//
#include <hip/hip_runtime.h>
#include <stdint.h>

#define T_STEPS 512
#define BATCH   512
#define DIN     128
#define HID     256
#define NCLS    1000

typedef unsigned int u32;
typedef unsigned long long u64;
typedef __attribute__((ext_vector_type(8))) short  short8;
typedef __attribute__((ext_vector_type(4))) short  short4v;
typedef __attribute__((ext_vector_type(4))) float  f32x4;

__device__ __forceinline__ short f2bf(float f){
  u32 u = __float_as_uint(f);
  u32 r = (u + 0x7FFFu + ((u >> 16) & 1u)) >> 16;   // RNE
  return (short)r;
}
__device__ __forceinline__ float bf2f(unsigned short s){
  return __uint_as_float(((u32)s) << 16);
}
__device__ __forceinline__ short8 cvt8(f32x4 a, f32x4 b){
  short8 v;
  v[0]=f2bf(a[0]); v[1]=f2bf(a[1]); v[2]=f2bf(a[2]); v[3]=f2bf(a[3]);
  v[4]=f2bf(b[0]); v[5]=f2bf(b[1]); v[6]=f2bf(b[2]); v[7]=f2bf(b[3]);
  return v;
}
// async global->LDS, 16B per lane; lds dest = wave-uniform base + lane*16 (HW)
__device__ __forceinline__ void gload_lds16(const void* g, void* l){
  __builtin_amdgcn_global_load_lds(
      (const __attribute__((address_space(1))) unsigned int*)g,
      (__attribute__((address_space(3))) unsigned int*)l, 16, 0, 0);
}

// ---------------------------------------------------------------------------
// Pack W_ih (768x128) / W_hh (768x256) fp32 -> bf16 frags P[kb][j][0..7],
// frag(kt,g4,j) = P[kt*4+g4][j]  (validated layout: R1/R3/R5/R6 passed).
// ---------------------------------------------------------------------------
__global__ __launch_bounds__(256) void pack_weights(
    const float* __restrict__ Wih, const float* __restrict__ Whh,
    short* __restrict__ PIH, short* __restrict__ PHH)
{
  int idx = blockIdx.x * 256 + threadIdx.x;   // 16*768 + 32*768
  if (idx >= 48*768) return;
  const float* src; short* dst;
  if (idx < 16*768){
    int kb = idx / 768, j = idx - kb*768;
    src = Wih + (size_t)j*DIN + kb*8;
    dst = PIH + (size_t)idx*8;
  } else {
    int i2 = idx - 16*768;
    int kb = i2 / 768, j = i2 - kb*768;
    src = Whh + (size_t)j*HID + kb*8;
    dst = PHH + (size_t)i2*8;
  }
  short8 v;
  #pragma unroll
  for (int e=0;e<8;e++) v[e] = f2bf(src[e]);
  *(short8*)dst = v;
}

// ---------------------------------------------------------------------------
// drop_mask fp32 (T,B,H) -> bitmask MB[t][gb(=b>>3)][r(=b&7)][32B], 1 bit/u.
// ---------------------------------------------------------------------------
__global__ __launch_bounds__(256) void mask_bits(
    const float* __restrict__ mask, unsigned char* __restrict__ MBo)
{
  int idx = blockIdx.x*256 + threadIdx.x;      // 512*512*32 = 8388608
  int t = idx >> 14, rem = idx & 16383, bb = rem >> 5, ub = rem & 31;
  const float* mp = mask + ((size_t)t*BATCH + bb)*HID + ub*8;
  u32 byte = 0;
  #pragma unroll
  for (int e=0;e<8;e++) byte |= (mp[e] > 0.5f ? 1u : 0u) << e;
  MBo[((size_t)t*64 + (bb>>3))*256 + (bb&7)*32 + ub] = (unsigned char)byte;
}

// ---------------------------------------------------------------------------
// gi = x @ W_ih^T + b_ih (+ b_hh for r,z).  Per (gb,t) output image (8KB+8KB):
//   RZ bf16: row b (8) x 512 cols (r: j<256, z: j-256) ; N fp32: 8 x 256.
// ---------------------------------------------------------------------------
__global__ __launch_bounds__(512, 1) void gi_gemm(
    const float* __restrict__ x, const float* __restrict__ b_ih,
    const float* __restrict__ b_hh, const short* __restrict__ PIH,
    short* __restrict__ GIbf, float* __restrict__ GIn)
{
  __shared__ __align__(16) short XT[64*136];   // A-tile bf16
  __shared__ __align__(16) short ORZ[16*520];  // RZ images (2 t's)
  __shared__ __align__(16) float ON [16*264];  // N  images
  const int tid = threadIdx.x;
  const int gb  = blockIdx.x >> 6;
  const int tc  = blockIdx.x & 63;
  const int tp0 = tc*4;
  const int w = tid>>6, l = tid&63, c = l&15, g4 = l>>4;

  short8 bfr[6][4]; float bj[6];
  #pragma unroll
  for (int q=0;q<6;q++){
    const int j = (w*6+q)*16 + c;
    #pragma unroll
    for (int kt=0;kt<4;kt++)
      bfr[q][kt] = *(const short8*)(PIH + ((size_t)(kt*4+g4)*768 + j)*8);
    bj[q] = b_ih[j] + (j < 512 ? b_hh[j] : 0.f);
  }

  {
    const int row = tid>>3, cc = (tid&7)*16;
    const int r = row&7, tpl = row>>4, tt = (row>>3)&1;
    const int bb = gb*8 + r;
    const int t  = (tp0+tpl)*2 + tt;
    const float* src = x + ((size_t)bb*T_STEPS + t)*DIN + cc;
    f32x4 a0 = *(const f32x4*)src,     a1 = *(const f32x4*)(src+4);
    f32x4 a2 = *(const f32x4*)(src+8), a3 = *(const f32x4*)(src+12);
    *(short8*)&XT[row*136 + cc]     = cvt8(a0,a1);
    *(short8*)&XT[row*136 + cc + 8] = cvt8(a2,a3);
  }
  __syncthreads();

  const f32x4 z4 = {0.f,0.f,0.f,0.f};
  #pragma unroll 1
  for (int mt=0; mt<4; ++mt){
    f32x4 acc[6];
    #pragma unroll
    for (int q=0;q<6;q++) acc[q] = z4;
    #pragma unroll
    for (int kt=0;kt<4;kt++){
      short8 af = *(const short8*)&XT[(mt*16+c)*136 + kt*32 + g4*8];
      #pragma unroll
      for (int q=0;q<6;q++)
        acc[q] = __builtin_amdgcn_mfma_f32_16x16x32_bf16(af, bfr[q][kt], acc[q], 0,0,0);
    }
    #pragma unroll
    for (int q=0;q<6;q++){
      const int j = (w*6+q)*16 + c;
      #pragma unroll
      for (int i=0;i<4;i++){
        const int r16 = g4*4+i;
        const float v = acc[q][i] + bj[q];
        if (j < 512) ORZ[r16*520 + j] = f2bf(v);
        else         ON [r16*264 + (j-512)] = v;
      }
    }
    __syncthreads();
    {
      const size_t gbase = (size_t)gb*2097152;   // shorts
      #pragma unroll
      for (int pass=0; pass<2; ++pass){
        const int chunk = pass*512 + tid;
        const int tt  = chunk >> 9;
        const int rem = chunk & 511;
        const int row = rem >> 6, c16 = rem & 63;
        short8 vv = *(const short8*)&ORZ[(tt*8+row)*520 + c16*8];
        const int t = (tp0+mt)*2 + tt;
        *(short8*)(GIbf + gbase + (size_t)t*4096 + rem*8) = vv;
      }
      const size_t nbase = (size_t)gb*1048576;   // floats
      #pragma unroll
      for (int pass=0; pass<2; ++pass){
        const int chunk = pass*512 + tid;
        const int tt  = chunk >> 9;
        const int rem = chunk & 511;
        const int row = rem >> 6, c4 = rem & 63;
        f32x4 vv = *(const f32x4*)&ON[(tt*8+row)*264 + c4*4];
        const int t = (tp0+mt)*2 + tt;
        *(f32x4*)(GIn + nbase + (size_t)t*2048 + rem*4) = vv;
      }
    }
    __syncthreads();
  }
}

// ---------------------------------------------------------------------------
// Persistent scan: 64 blocks x 8 batch rows, 512 thr (8 waves).
// W_hh register-resident: 48 frags/lane, pinned via "+v" inout asm (values
// become asm outputs -> cannot be rematerialized by reloading).
// gi staged via global_load_lds, QUAD-buffered, stage(t+2) issued at step
// start; end-of-step s_waitcnt vmcnt(3) keeps 2-step prefetch in flight
// (exactly 3 VM ops/step: 2 gload_lds + 1 mask byte, bounded by clobbers).
// ---------------------------------------------------------------------------
__global__ __launch_bounds__(512, 2) void gru_scan(
    const float* __restrict__ b_hh, const unsigned char* __restrict__ MB,
    const short* __restrict__ PHH, const short* __restrict__ GIbf,
    const float* __restrict__ GIn, float* __restrict__ HFIN)
{
  __shared__ __align__(16) short Ah[16*264];     // h bf16 A-tile (rows 8..15 zero)
  __shared__ __align__(16) float Gs[8*776];      // gh spill
  __shared__ __align__(16) short GiRZ[4][8*512]; // gi r,z bf16, quad buffer
  __shared__ __align__(16) float GiN [4][8*256]; // gi n fp32, quad buffer

  const int tid = threadIdx.x;
  const int gb  = blockIdx.x;
  const int w = tid>>6, l = tid&63, c = l&15, g4 = l>>4;
  const int b  = tid>>6;
  const int u4 = (tid&63)*4;

  // bias load BEFORE the pin (clobbers forbid sinking it into the loop region)
  const f32x4 bhn4 = *(const f32x4*)(b_hh + 512 + u4);

  // ---- W_hh fragments -> registers (once) ----
  short8 whf[6][8];
  #pragma unroll
  for (int q=0;q<6;q++){
    const int j = (w*6+q)*16 + c;
    #pragma unroll
    for (int kt=0;kt<8;kt++)
      whf[q][kt] = *(const short8*)(PHH + ((size_t)(kt*4+g4)*768 + j)*8);
  }
  // ---- pin: redefine every fragment as an asm output (remat-proof) ----
#define PIN4(a,b_,c_,d_) asm volatile("" : "+v"(a), "+v"(b_), "+v"(c_), "+v"(d_))
  #pragma unroll
  for (int q=0;q<6;q++){
    PIN4(whf[q][0], whf[q][1], whf[q][2], whf[q][3]);
    PIN4(whf[q][4], whf[q][5], whf[q][6], whf[q][7]);
  }
#undef PIN4

  const int mboff  = b*32 + ((tid&63)>>1);
  const int mshift = ((tid&63)&1) << 2;

  for (int i=tid; i<16*264; i+=512) Ah[i] = 0;

  const char* srz = (const char*)GIbf + (size_t)gb*4194304;
  const char* sn  = (const char*)GIn  + (size_t)gb*4194304;
  const int gioff = w*1024 + l*16;
  const int ar_off = c*264;
  const int gbase  = (g4*4)*776 + w*96 + c;

  // ---- prologue: stage t=0,1 + masks; full drain ----
  gload_lds16(srz + (size_t)0*8192 + gioff, (char*)&GiRZ[0][w*512]);
  gload_lds16(sn  + (size_t)0*8192 + gioff, (char*)&GiN [0][w*256]);
  u32 mk0 = MB[(size_t)gb*256 + mboff];
  gload_lds16(srz + (size_t)1*8192 + gioff, (char*)&GiRZ[1][w*512]);
  gload_lds16(sn  + (size_t)1*8192 + gioff, (char*)&GiN [1][w*256]);
  u32 mk1 = MB[((size_t)64 + gb)*256 + mboff];
  u32 mk2 = 0, mk3 = 0;
  float hreg[4] = {0.f,0.f,0.f,0.f};

  asm volatile("s_waitcnt vmcnt(0) lgkmcnt(0)" ::: "memory");
  __builtin_amdgcn_s_barrier();

#define STEP(T, P, MC, MN, DOISS, VMN) {                                       \
  /* 1. issue stage(T+2) -> buf (P+2)&3  (exactly 3 VM ops when DOISS) */      \
  if (DOISS){                                                                  \
    gload_lds16(srz + (size_t)((T)+2)*8192 + gioff,                            \
                (char*)&GiRZ[((P)+2)&3][w*512]);                               \
    gload_lds16(sn  + (size_t)((T)+2)*8192 + gioff,                            \
                (char*)&GiN [((P)+2)&3][w*256]);                               \
    MN = MB[((size_t)((T)+2)*64 + gb)*256 + mboff];                            \
  }                                                                            \
  /* 2. gh = h @ W_hh^T : 48 MFMA / wave */                                    \
  f32x4 acc[6];                                                                \
  _Pragma("unroll") for (int q=0;q<6;q++){                                     \
    acc[q][0]=0.f; acc[q][1]=0.f; acc[q][2]=0.f; acc[q][3]=0.f; }              \
  _Pragma("unroll") for (int kt=0;kt<8;kt++){                                  \
    short8 af = *(const short8*)&Ah[ar_off + kt*32 + g4*8];                    \
    _Pragma("unroll") for (int q=0;q<6;q++)                                    \
      acc[q] = __builtin_amdgcn_mfma_f32_16x16x32_bf16(af, whf[q][kt], acc[q], 0,0,0); \
  }                                                                            \
  /* 3. spill rows 0..7 (C/D: col=c, row=g4*4+i) */                            \
  if (g4 < 2){                                                                 \
    _Pragma("unroll") for (int q=0;q<6;q++){                                   \
      _Pragma("unroll") for (int i=0;i<4;i++)                                  \
        Gs[gbase + i*776 + q*16] = acc[q][i];                                  \
    }                                                                          \
  }                                                                            \
  /* 4. mid barrier (LDS only; VMEM stays in flight) */                        \
  asm volatile("s_waitcnt lgkmcnt(0)" ::: "memory");                           \
  __builtin_amdgcn_sched_barrier(0);                                           \
  __builtin_amdgcn_s_barrier();                                                \
  __builtin_amdgcn_sched_barrier(0);                                           \
  /* 5. gates */                                                               \
  {                                                                            \
    f32x4 gr = *(const f32x4*)&Gs[b*776       + u4];                           \
    f32x4 gz = *(const f32x4*)&Gs[b*776 + 256 + u4];                           \
    f32x4 gn = *(const f32x4*)&Gs[b*776 + 512 + u4];                           \
    short4v sr = *(const short4v*)&GiRZ[P][b*512       + u4];                  \
    short4v sz = *(const short4v*)&GiRZ[P][b*512 + 256 + u4];                  \
    f32x4 gin = *(const f32x4*)&GiN[P][b*256 + u4];                            \
    _Pragma("unroll") for (int e=0;e<4;e++){                                   \
      float r_ = 1.f/(1.f + __expf(-(gr[e] + bf2f((unsigned short)sr[e]))));   \
      float z_ = 1.f/(1.f + __expf(-(gz[e] + bf2f((unsigned short)sz[e]))));   \
      float e2 = __expf(2.f*(gin[e] + r_*(gn[e] + bhn4[e])));                  \
      float n_ = 1.f - 2.f/(e2 + 1.f);                                         \
      float mv = ((MC >> (mshift + e)) & 1u) ? 1.3333334f : 0.f;               \
      hreg[e] = ((1.f - z_)*n_ + z_*hreg[e]) * mv;                             \
    }                                                                          \
    short4v hv;                                                                \
    hv[0]=f2bf(hreg[0]); hv[1]=f2bf(hreg[1]);                                  \
    hv[2]=f2bf(hreg[2]); hv[3]=f2bf(hreg[3]);                                  \
    *(short4v*)&Ah[b*264 + u4] = hv;                                           \
  }                                                                            \
  /* 6. end barrier: stage(T+1) drained (3 newest = this step's ops) */        \
  asm volatile("s_waitcnt vmcnt(" #VMN ") lgkmcnt(0)" ::: "memory");           \
  __builtin_amdgcn_sched_barrier(0);                                           \
  __builtin_amdgcn_s_barrier();                                                \
  __builtin_amdgcn_sched_barrier(0);                                           \
}

  #pragma unroll 1
  for (int t=0; t<508; t+=4){
    STEP(t,   0, mk0, mk2, 1, 3);
    STEP(t+1, 1, mk1, mk3, 1, 3);
    STEP(t+2, 2, mk2, mk0, 1, 3);
    STEP(t+3, 3, mk3, mk1, 1, 3);
  }
  STEP(508, 0, mk0, mk2, 1, 3);
  STEP(509, 1, mk1, mk3, 1, 3);
  STEP(510, 2, mk2, mk0, 0, 0);   // no new issues: drain stage(511)
  STEP(511, 3, mk3, mk1, 0, 0);
#undef STEP

  f32x4 hv; hv[0]=hreg[0]; hv[1]=hreg[1]; hv[2]=hreg[2]; hv[3]=hreg[3];
  *(f32x4*)&HFIN[((size_t)(gb*8 + b))*HID + u4] = hv;
}

// ---------------------------------------------------------------------------
// out = h @ W_out^T + b_out   (512x256 @ 256x1000), fp32 vector.
// ---------------------------------------------------------------------------
__global__ __launch_bounds__(256) void out_gemm(
    const float* __restrict__ Hf, const float* __restrict__ Wout,
    const float* __restrict__ bout, float* __restrict__ out)
{
  __shared__ __align__(16) float hl[16*256];
  const int bb0 = (blockIdx.x >> 4) * 16;
  const int cc0 = (blockIdx.x & 15) * 64;
  for (int i=threadIdx.x; i<16*256; i+=256) hl[i] = Hf[(size_t)bb0*HID + i];
  __syncthreads();
  const int cc = cc0 + (threadIdx.x & 63);
  const int br = threadIdx.x >> 6;
  if (cc >= NCLS) return;
  const f32x4* wr = (const f32x4*)(Wout + (size_t)cc*HID);
  float a0=0.f, a1=0.f, a2=0.f, a3=0.f;
  #pragma unroll 8
  for (int k4=0;k4<64;k4++){
    f32x4 wv = wr[k4];
    #pragma unroll
    for (int e=0;e<4;e++){
      float we = wv[e]; int k = k4*4+e;
      a0 += hl[(br   )*256+k]*we;
      a1 += hl[(br+ 4)*256+k]*we;
      a2 += hl[(br+ 8)*256+k]*we;
      a3 += hl[(br+12)*256+k]*we;
    }
  }
  float bo = bout[cc];
  out[(size_t)(bb0+br   )*NCLS + cc] = a0 + bo;
  out[(size_t)(bb0+br+ 4)*NCLS + cc] = a1 + bo;
  out[(size_t)(bb0+br+ 8)*NCLS + cc] = a2 + bo;
  out[(size_t)(bb0+br+12)*NCLS + cc] = a3 + bo;
}

// ---------------------------------------------------------------------------
extern "C" void kernel_launch(void* const* d_in, const int* in_sizes, int n_in,
                              void* d_out, int out_size, void* d_ws, size_t ws_size,
                              hipStream_t stream) {
  const float* x     = (const float*)d_in[0];
  const float* W_ih  = (const float*)d_in[1];
  const float* W_hh  = (const float*)d_in[2];
  const float* b_ih  = (const float*)d_in[3];
  const float* b_hh  = (const float*)d_in[4];
  const float* W_out = (const float*)d_in[5];
  const float* b_out = (const float*)d_in[6];
  const float* dmask = (const float*)d_in[7];

  // ws layout (bytes):
  //   PIH   0         .. 196608
  //   PHH   196608    .. 589824
  //   HFIN  589824    .. 1114112
  //   MB    1114112   .. 9502720
  //   GIbf  9502720   .. 277938176   (64 gb * 512 t * 8KB)
  //   GIn   277938176 .. 546373632   (64 gb * 512 t * 8KB)
  if (ws_size < 546373632ull) return;   // clean fail if scratch too small
  short* PIH  = (short*)d_ws;
  short* PHH  = (short*)((char*)d_ws + 196608);
  float* HFIN = (float*)((char*)d_ws + 589824);
  unsigned char* MBp = (unsigned char*)d_ws + 1114112;
  short* GIbf = (short*)((char*)d_ws + 9502720);
  float* GIn  = (float*)((char*)d_ws + 277938176);

  pack_weights<<<144, 256, 0, stream>>>(W_ih, W_hh, PIH, PHH);
  mask_bits<<<32768, 256, 0, stream>>>(dmask, MBp);
  gi_gemm<<<4096, 512, 0, stream>>>(x, b_ih, b_hh, PIH, GIbf, GIn);
  gru_scan<<<64, 512, 0, stream>>>(b_hh, MBp, PHH, GIbf, GIn, HFIN);
  out_gemm<<<512, 256, 0, stream>>>(HFIN, W_out, b_out, (float*)d_out);
}